// Round 1
// baseline (4000.122 us; speedup 1.0000x reference)
//
#include <hip/hip_runtime.h>

#define BB    2      // batches
#define NN    8192   // points per batch
#define CC    64     // extra feature channels
#define DD    67     // total dims (3 + 64)
#define NPT   1024   // npoint
#define NBLK  16     // blocks per batch
#define TPB   512    // threads per block (1 point per thread)

// monotonic order-preserving key for f32 (handles negatives)
__device__ __forceinline__ unsigned int fkey(float v) {
  unsigned int u = __float_as_uint(v);
  return (u & 0x80000000u) ? ~u : (u | 0x80000000u);
}

__global__ __launch_bounds__(TPB) void fps_kernel(
    const float* __restrict__ pts,   // (B, N, 3)
    const float* __restrict__ feat,  // (B, C, N)
    int* __restrict__ out,           // (B, NPT)
    float* __restrict__ norms,       // ws: (B, N)
    unsigned long long* __restrict__ slots, // ws: [2][B][NBLK]
    unsigned int* __restrict__ ctr)         // ws: [B]
{
  const int blk = blockIdx.x & (NBLK - 1);
  const int b   = blockIdx.x >> 4;
  const int tid = threadIdx.x;
  const int p   = blk * TPB + tid;   // this thread's point

  // ---- load this point's 67-dim feature vector into registers (coalesced)
  float f[DD];
  {
    const float* P = pts + (size_t)b * NN * 3 + (size_t)p * 3;
    f[0] = P[0]; f[1] = P[1]; f[2] = P[2];
    const float* F = feat + (size_t)b * CC * NN + p;
#pragma unroll
    for (int c = 0; c < CC; ++c) f[3 + c] = F[(size_t)c * NN];
  }

  // ---- norm (sequential order, matches our self-dot exactly -> d(far,far)==0)
  float nrm = 0.f;
#pragma unroll
  for (int c = 0; c < DD; ++c) nrm += f[c] * f[c];
  __hip_atomic_store(&norms[b * NN + p], nrm, __ATOMIC_RELAXED, __HIP_MEMORY_SCOPE_AGENT);

  __shared__ unsigned long long wred[TPB / 64];
  __shared__ int far_sh;

  // ---- init barrier: publish norms (ctr was zeroed by hipMemsetAsync)
  __syncthreads();
  if (tid == 0) {
    __hip_atomic_fetch_add(&ctr[b], 1u, __ATOMIC_RELEASE, __HIP_MEMORY_SCOPE_AGENT);
    while (__hip_atomic_load(&ctr[b], __ATOMIC_ACQUIRE, __HIP_MEMORY_SCOPE_AGENT) < NBLK) {}
  }
  __syncthreads();

  if (blk == 0 && tid == 0) out[b * NPT + 0] = 0;

  float mind = 3.0e38f;
  int far = 0;

  for (int s = 1; s < NPT; ++s) {
    // ---- update mind with distance to `far` (uniform broadcast reads)
    {
      const int fu = __builtin_amdgcn_readfirstlane(far);
      const float* Pf = pts + (size_t)b * NN * 3 + (size_t)fu * 3;
      const float* Ff = feat + (size_t)b * CC * NN + fu;
      const float nf = __hip_atomic_load(&norms[b * NN + fu], __ATOMIC_RELAXED,
                                         __HIP_MEMORY_SCOPE_AGENT);
      float dot = 0.f;
      dot += f[0] * Pf[0];
      dot += f[1] * Pf[1];
      dot += f[2] * Pf[2];
#pragma unroll
      for (int c = 0; c < CC; ++c) dot += f[3 + c] * Ff[(size_t)c * NN];
      const float d = (nf + nrm) - 2.0f * dot;
      mind = fminf(mind, d);
    }

    // ---- block argmax of mind (key: value desc, then lowest index)
    unsigned long long key =
        ((unsigned long long)fkey(mind) << 32) | (unsigned int)(~p);
#pragma unroll
    for (int off = 32; off; off >>= 1) {
      unsigned long long o = __shfl_xor(key, off);
      key = (key > o) ? key : o;
    }
    const int lane = tid & 63, wid = tid >> 6;
    if (lane == 0) wred[wid] = key;
    __syncthreads();

    // ---- grid argmax via slots + per-batch arrival counter
    if (tid == 0) {
      unsigned long long bk = wred[0];
#pragma unroll
      for (int w = 1; w < TPB / 64; ++w) bk = (bk > wred[w]) ? bk : wred[w];
      unsigned long long* slot = slots + ((size_t)(s & 1) * BB + b) * NBLK;
      __hip_atomic_store(&slot[blk], bk, __ATOMIC_RELAXED, __HIP_MEMORY_SCOPE_AGENT);
      __hip_atomic_fetch_add(&ctr[b], 1u, __ATOMIC_RELEASE, __HIP_MEMORY_SCOPE_AGENT);
      const unsigned int tgt = (unsigned int)NBLK * (unsigned int)(s + 1);
      while (__hip_atomic_load(&ctr[b], __ATOMIC_ACQUIRE, __HIP_MEMORY_SCOPE_AGENT) < tgt) {}
    }
    __syncthreads();

    unsigned long long gk = 0;
    if (tid < 64) {
      const unsigned long long* slot = slots + ((size_t)(s & 1) * BB + b) * NBLK;
      if (tid < NBLK)
        gk = __hip_atomic_load(&slot[tid], __ATOMIC_RELAXED, __HIP_MEMORY_SCOPE_AGENT);
#pragma unroll
      for (int off = 8; off; off >>= 1) {
        unsigned long long o = __shfl_xor(gk, off);
        gk = (gk > o) ? gk : o;
      }
      if (tid == 0) far_sh = (int)(~(unsigned int)gk);
    }
    __syncthreads();
    far = far_sh;
    if (blk == 0 && tid == 0) out[b * NPT + s] = far;
  }
}

extern "C" void kernel_launch(void* const* d_in, const int* in_sizes, int n_in,
                              void* d_out, int out_size, void* d_ws, size_t ws_size,
                              hipStream_t stream) {
  const float* pts  = (const float*)d_in[0];
  const float* feat = (const float*)d_in[1];
  int* out = (int*)d_out;

  float* norms = (float*)d_ws;                                   // 64 KiB
  unsigned long long* slots =
      (unsigned long long*)((char*)d_ws + 65536);                // 512 B
  unsigned int* ctr = (unsigned int*)((char*)d_ws + 65536 + 512);// 8 B

  // zero the barrier region every call (replay-deterministic)
  hipMemsetAsync((char*)d_ws + 65536, 0, 1024, stream);

  void* args[] = {(void*)&pts, (void*)&feat, (void*)&out,
                  (void*)&norms, (void*)&slots, (void*)&ctr};
  dim3 grid(BB * NBLK), block(TPB);
  hipLaunchCooperativeKernel((void*)fps_kernel, grid, block, args, 0, stream);
}

// Round 2
// 3057.243 us; speedup vs baseline: 1.3084x; 1.3084x over previous
//
#include <hip/hip_runtime.h>

#define BB    2      // batches
#define NN    8192   // points per batch
#define CC    64     // extra feature channels
#define DD    67     // total dims (3 + 64)
#define NPT   1024   // npoint
#define NBLK  16     // blocks per batch
#define TPB   512    // threads per block (1 point per thread)

// monotonic order-preserving key for f32 (handles negatives)
__device__ __forceinline__ unsigned int fkey(float v) {
  unsigned int u = __float_as_uint(v);
  return (u & 0x80000000u) ? ~u : (u | 0x80000000u);
}

__global__ __launch_bounds__(TPB, 1) void fps_kernel(
    const float* __restrict__ pts,   // (B, N, 3)
    const float* __restrict__ feat,  // (B, C, N)
    int* __restrict__ out,           // (B, NPT)
    float* __restrict__ norms,       // ws: (B, N)
    unsigned long long* __restrict__ slots, // ws: [B][NBLK]
    unsigned int* __restrict__ ctr)         // ws: [B]
{
  const int blk = blockIdx.x & (NBLK - 1);
  const int b   = blockIdx.x >> 4;
  const int tid = threadIdx.x;
  const int p   = blk * TPB + tid;   // this thread's point

  // ---- load this point's 67-dim feature vector (coalesced), pin in VGPRs
  float f[DD];
  {
    const float* P = pts + (size_t)b * NN * 3 + (size_t)p * 3;
    f[0] = P[0]; f[1] = P[1]; f[2] = P[2];
    const float* F = feat + (size_t)b * CC * NN + p;
#pragma unroll
    for (int c = 0; c < CC; ++c) f[3 + c] = F[(size_t)c * NN];
  }
#pragma unroll
  for (int c = 0; c < DD; ++c) asm volatile("" : "+v"(f[c]));  // force VGPR residency

  // ---- norm (sequential order, matches self-dot exactly -> d(far,far)==0)
  float nrm = 0.f;
#pragma unroll
  for (int c = 0; c < DD; ++c) nrm += f[c] * f[c];
  __hip_atomic_store(&norms[b * NN + p], nrm, __ATOMIC_RELAXED, __HIP_MEMORY_SCOPE_AGENT);

  __shared__ unsigned long long wred[TPB / 64];
  __shared__ int far_sh;

  // ---- one-time init barrier: publish norms (ctr zeroed by hipMemsetAsync)
  __syncthreads();
  if (tid == 0) {
    __hip_atomic_fetch_add(&ctr[b], 1u, __ATOMIC_RELEASE, __HIP_MEMORY_SCOPE_AGENT);
    while (__hip_atomic_load(&ctr[b], __ATOMIC_ACQUIRE, __HIP_MEMORY_SCOPE_AGENT) < NBLK) {}
  }
  __syncthreads();

  if (blk == 0 && tid == 0) out[b * NPT + 0] = 0;

  float mind = 3.0e38f;
  int far = 0;

  unsigned long long* const slot = slots + (size_t)b * NBLK;  // 128 B, contiguous

  for (int s = 1; s < NPT; ++s) {
    // ---- update mind with distance to `far` (uniform broadcast reads)
    {
      const int fu = __builtin_amdgcn_readfirstlane(far);
      const float* Pf = pts + (size_t)b * NN * 3 + (size_t)fu * 3;
      const float* Ff = feat + (size_t)b * CC * NN + fu;
      const float nf = __hip_atomic_load(&norms[b * NN + fu], __ATOMIC_RELAXED,
                                         __HIP_MEMORY_SCOPE_AGENT);
      float dot = 0.f;
      dot += f[0] * Pf[0];
      dot += f[1] * Pf[1];
      dot += f[2] * Pf[2];
#pragma unroll
      for (int c = 0; c < CC; ++c) dot += f[3 + c] * Ff[(size_t)c * NN];
      const float d = (nf + nrm) - 2.0f * dot;
      mind = fminf(mind, d);
    }

    // ---- block argmax: key = (value desc, lowest index). idx in low 13 bits.
    unsigned long long key =
        ((unsigned long long)fkey(mind) << 13) | (unsigned int)(8191 - p);
#pragma unroll
    for (int off = 32; off; off >>= 1) {
      unsigned long long o = __shfl_xor(key, off);
      key = (key > o) ? key : o;
    }
    if ((tid & 63) == 0) wred[tid >> 6] = key;
    __syncthreads();

    // ---- grid argmax: tagged slots, single-phase (no counter round trips)
    if (tid < 64) {
      unsigned long long bk = wred[0];
#pragma unroll
      for (int w = 1; w < TPB / 64; ++w) bk = (bk > wred[w]) ? bk : wred[w];
      if (tid == 0) {
        bk |= ((unsigned long long)s << 45);   // tag with step
        __hip_atomic_store(&slot[blk], bk, __ATOMIC_RELEASE, __HIP_MEMORY_SCOPE_AGENT);
      }
      // poll all 16 slots (one coalesced 128B request) until every tag == s
      unsigned long long v = 0;
      for (;;) {
        if (tid < NBLK)
          v = __hip_atomic_load(&slot[tid], __ATOMIC_RELAXED, __HIP_MEMORY_SCOPE_AGENT);
        const bool ok = (tid < NBLK) ? ((v >> 45) == (unsigned long long)s) : true;
        if (__all(ok)) break;
      }
      // max-reduce the 16 polled values (offsets <=8 stay within lanes 0..15)
#pragma unroll
      for (int off = 8; off; off >>= 1) {
        unsigned long long o = __shfl_xor(v, off);
        v = (v > o) ? v : o;
      }
      if (tid == 0) far_sh = 8191 - (int)(v & 0x1FFF);
    }
    __syncthreads();
    far = far_sh;
    if (blk == 0 && tid == 0) out[b * NPT + s] = far;
  }
}

extern "C" void kernel_launch(void* const* d_in, const int* in_sizes, int n_in,
                              void* d_out, int out_size, void* d_ws, size_t ws_size,
                              hipStream_t stream) {
  const float* pts  = (const float*)d_in[0];
  const float* feat = (const float*)d_in[1];
  int* out = (int*)d_out;

  float* norms = (float*)d_ws;                                    // 64 KiB
  unsigned long long* slots =
      (unsigned long long*)((char*)d_ws + 65536);                 // 256 B
  unsigned int* ctr = (unsigned int*)((char*)d_ws + 65536 + 256); // 8 B

  // zero the barrier region every call (replay-deterministic)
  hipMemsetAsync((char*)d_ws + 65536, 0, 512, stream);

  void* args[] = {(void*)&pts, (void*)&feat, (void*)&out,
                  (void*)&norms, (void*)&slots, (void*)&ctr};
  dim3 grid(BB * NBLK), block(TPB);
  hipLaunchCooperativeKernel((void*)fps_kernel, grid, block, args, 0, stream);
}